// Round 17
// baseline (260.879 us; speedup 1.0000x reference)
//
#include <hip/hip_runtime.h>

#define N_NODES 50000
#define NRANGE 8
#define RNG 6400          // NRANGE*RNG = 51200 >= N
#define TOTR (NRANGE * RNG)
#define NCHUNK 32

using f32x4  = __attribute__((ext_vector_type(4))) float;
using bf16x8 = __attribute__((ext_vector_type(8))) __bf16;

__device__ __forceinline__ unsigned short f2bf(float f) {
    unsigned int b = __float_as_uint(f);
    unsigned int r = (b + 0x7FFFu + ((b >> 16) & 1u)) >> 16;   // RNE
    return (unsigned short)r;
}
__device__ __forceinline__ float bf_lo(unsigned int u) { return __uint_as_float(u << 16); }
__device__ __forceinline__ float bf_hi(unsigned int u) { return __uint_as_float(u & 0xFFFF0000u); }
__device__ __forceinline__ unsigned int packbf(float x, float y) {
    return ((unsigned int)f2bf(y) << 16) | f2bf(x);
}

// ---------------- utility ----------------

__global__ void cvt_bf_kernel(const float* __restrict__ in, unsigned short* __restrict__ out, size_t n4) {
    size_t i = (size_t)blockIdx.x * blockDim.x + threadIdx.x;
    if (i < n4) {
        float4 v = *reinterpret_cast<const float4*>(in + i * 4);
        ushort4 o;
        o.x = f2bf(v.x); o.y = f2bf(v.y); o.z = f2bf(v.z); o.w = f2bf(v.w);
        *reinterpret_cast<ushort4*>(out + i * 4) = o;
    }
}

// W1: [3][128][256] f32 -> Bt1: [256][384] bf16
__global__ void wtrans1_kernel(const float* __restrict__ W, unsigned short* __restrict__ Bt) {
    int i = blockIdx.x * blockDim.x + threadIdx.x;
    if (i < 3 * 128 * 256) {
        int c = i % 256;
        int kg = i / 256;
        Bt[(size_t)c * 384 + kg] = f2bf(W[(size_t)kg * 256 + c]);
    }
}

// W2: [3][256][128] f32 -> Btc: [384][256] bf16 with cols [W0-W2 | W1 | 2*W2]
__global__ void wtrans2_kernel(const float* __restrict__ W, unsigned short* __restrict__ Btc) {
    int i = blockIdx.x * blockDim.x + threadIdx.x;
    if (i < 384 * 256) {
        int k = i % 256;
        int cc = i / 256;
        int seg = cc >> 7, c = cc & 127;
        float v;
        if (seg == 0)      v = W[(size_t)k * 128 + c] - W[(size_t)(2 * 256 + k) * 128 + c];
        else if (seg == 1) v = W[(size_t)(256 + k) * 128 + c];
        else               v = 2.0f * W[(size_t)(2 * 256 + k) * 128 + c];
        Btc[(size_t)cc * 256 + k] = f2bf(v);
    }
}

// ---------------- edge preprocessing: privatized LDS histograms ----------------

__global__ __launch_bounds__(1024) void hist_priv_kernel(
        const int* __restrict__ src, const int* __restrict__ dst, int E, int chunk,
        int* __restrict__ pd, int* __restrict__ pc) {     // [NCHUNK][TOTR] each
    __shared__ int lhS[RNG];
    __shared__ int lhD[RNG];
    int r = blockIdx.x & (NRANGE - 1);
    int c = blockIdx.x >> 3;               // NRANGE == 8
    int lo = r * RNG;
    for (int i = threadIdx.x; i < RNG; i += 1024) { lhS[i] = 0; lhD[i] = 0; }
    __syncthreads();
    int e0 = c * chunk, e1 = min(e0 + chunk, E);
    for (int e = e0 + threadIdx.x; e < e1; e += 1024) {
        int s = src[e], d = dst[e];
        if (s != d) {
            unsigned int sr = (unsigned int)(s - lo);
            unsigned int dr = (unsigned int)(d - lo);
            if (sr < RNG) atomicAdd(&lhS[sr], 1);
            if (dr < RNG) atomicAdd(&lhD[dr], 1);
        }
    }
    __syncthreads();
    int base = c * TOTR + lo;
    for (int i = threadIdx.x; i < RNG; i += 1024) {
        pd[base + i] = lhS[i];
        pc[base + i] = lhD[i];
    }
}

__global__ void reduce_chunks_kernel(int* __restrict__ pd, int* __restrict__ pc,
                                     float* __restrict__ dinv, int* __restrict__ cnt, int n) {
    int i = blockIdx.x * blockDim.x + threadIdx.x;
    if (i >= TOTR) return;
    int degs = 0;
#pragma unroll 8
    for (int c = 0; c < NCHUNK; ++c) degs += pd[c * TOTR + i];
    int run = 0;
#pragma unroll 8
    for (int c = 0; c < NCHUNK; ++c) {
        int v = pc[c * TOTR + i];
        pc[c * TOTR + i] = run;
        run += v;
    }
    if (i < n) {
        dinv[i] = degs > 0 ? rsqrtf((float)degs) : 0.0f;
        cnt[i] = run;
    }
}

// --- 3-phase scan over cnt -> rowptr ---

__global__ __launch_bounds__(1024) void scan1_kernel(const int* __restrict__ cnt,
                                                     int* __restrict__ excl,
                                                     int* __restrict__ bsum, int n) {
    __shared__ int wsum[16];
    int tid = threadIdx.x, lane = tid & 63, wid = tid >> 6;
    int i = blockIdx.x * 1024 + tid;
    int v = (i < n) ? cnt[i] : 0;
    int x = v;
#pragma unroll
    for (int o = 1; o < 64; o <<= 1) { int y = __shfl_up(x, o); if (lane >= o) x += y; }
    if (lane == 63) wsum[wid] = x;
    __syncthreads();
    if (tid < 16) {
        int s = wsum[tid];
#pragma unroll
        for (int o = 1; o < 16; o <<= 1) { int y = __shfl_up(s, o); if (tid >= o) s += y; }
        wsum[tid] = s;
    }
    __syncthreads();
    int base = (wid > 0 ? wsum[wid - 1] : 0);
    if (i < n) excl[i] = base + x - v;
    if (tid == 0) bsum[blockIdx.x] = wsum[15];
}

__global__ void scan2_kernel(int* __restrict__ bsum, int nb) {
    int t = threadIdx.x;                   // single wave, nb <= 64
    int v = (t < nb) ? bsum[t] : 0;
    int x = v;
#pragma unroll
    for (int o = 1; o < 64; o <<= 1) { int y = __shfl_up(x, o); if (t >= o) x += y; }
    if (t < nb) bsum[t] = x - v;           // exclusive
}

__global__ __launch_bounds__(1024) void scan3_kernel(const int* __restrict__ excl,
                                                     const int* __restrict__ bsum,
                                                     const int* __restrict__ cnt,
                                                     int* __restrict__ rowptr, int n) {
    int i = blockIdx.x * 1024 + threadIdx.x;
    if (i < n) {
        int rp = excl[i] + bsum[blockIdx.x];
        rowptr[i] = rp;
        if (i == n - 1) rowptr[n] = rp + cnt[i];
    }
}

// CSR placement with LDS cursors. csr packed as int2 {src, bitcast(fp32 w)}.
// NOTE (r16 lesson): placement order is nondeterministic (atomic cursors), so
// gather summation order varies across replays. Weights must stay FP32 —
// bf16-packing them (r16) pushed the replay-to-replay drift past threshold.
__global__ __launch_bounds__(1024) void csr_place_kernel(
        const int* __restrict__ src, const int* __restrict__ dst, int E, int chunk,
        const int* __restrict__ pc, const int* __restrict__ rowptr,
        const float* __restrict__ dinv,
        int2* __restrict__ csr, int n) {
    __shared__ int cur[RNG];
    __shared__ float dloc[RNG];
    int r = blockIdx.x & (NRANGE - 1);
    int c = blockIdx.x >> 3;
    int lo = r * RNG;
    for (int i = threadIdx.x; i < RNG; i += 1024) {
        int node = lo + i;
        if (node < n) {
            cur[i] = rowptr[node] + pc[c * TOTR + node];
            dloc[i] = dinv[node];
        }
    }
    __syncthreads();
    int e0 = c * chunk, e1 = min(e0 + chunk, E);
    for (int e = e0 + threadIdx.x; e < e1; e += 1024) {
        int s = src[e], d = dst[e];
        unsigned int dr = (unsigned int)(d - lo);
        if (s != d && dr < RNG) {
            int pos = atomicAdd(&cur[dr], 1);
            csr[pos] = make_int2(s, __float_as_int(-dinv[s] * dloc[dr]));
        }
    }
}

// ---------------- CSR gather propagation, D=128 bf16, f32 accum ----------------
// 16-wide first tier (avg deg ~16: the typical node's entire adjacency issues
// in ONE batch of outstanding loads), then 8/2/1 tails. Accumulation order is
// k-ascending in every tier -> bit-identical to the r12/r14 8-wide version.

__global__ void prop_kernel(const unsigned int* __restrict__ H, int hs,
                            const int* __restrict__ rowptr,
                            const int2* __restrict__ csr,
                            const unsigned int* __restrict__ add, int as_,
                            float scale, float coef,
                            unsigned int* __restrict__ out, int n) {
    int wib = threadIdx.x >> 6;
    int lane = threadIdx.x & 63;
    int node = blockIdx.x * (blockDim.x >> 6) + wib;
    if (node >= n) return;

    float ax = 0.0f, ay = 0.0f;
    int beg = rowptr[node], end = rowptr[node + 1];
    int i = beg;
    for (; i + 16 <= end; i += 16) {
        int2 e[16];
#pragma unroll
        for (int k = 0; k < 16; ++k) e[k] = csr[i + k];
        unsigned int u[16];
#pragma unroll
        for (int k = 0; k < 16; ++k) u[k] = H[(size_t)e[k].x * hs + lane];
#pragma unroll
        for (int k = 0; k < 16; ++k) {
            float wk = __int_as_float(e[k].y);
            ax += wk * bf_lo(u[k]);
            ay += wk * bf_hi(u[k]);
        }
    }
    for (; i + 8 <= end; i += 8) {
        int2 e[8];
#pragma unroll
        for (int k = 0; k < 8; ++k) e[k] = csr[i + k];
        unsigned int u[8];
#pragma unroll
        for (int k = 0; k < 8; ++k) u[k] = H[(size_t)e[k].x * hs + lane];
#pragma unroll
        for (int k = 0; k < 8; ++k) {
            float wk = __int_as_float(e[k].y);
            ax += wk * bf_lo(u[k]);
            ay += wk * bf_hi(u[k]);
        }
    }
    for (; i + 2 <= end; i += 2) {
        int2 e0 = csr[i], e1 = csr[i + 1];
        unsigned int u0 = H[(size_t)e0.x * hs + lane];
        unsigned int u1 = H[(size_t)e1.x * hs + lane];
        float w0 = __int_as_float(e0.y), w1 = __int_as_float(e1.y);
        ax += w0 * bf_lo(u0) + w1 * bf_lo(u1);
        ay += w0 * bf_hi(u0) + w1 * bf_hi(u1);
    }
    if (i < end) {
        int2 e0 = csr[i];
        unsigned int u0 = H[(size_t)e0.x * hs + lane];
        float w0 = __int_as_float(e0.y);
        ax += w0 * bf_lo(u0);
        ay += w0 * bf_hi(u0);
    }

    float vx = scale * ax, vy = scale * ay;
    if (add) {
        unsigned int au = add[(size_t)node * as_ + lane];
        vx += coef * bf_lo(au);
        vy += coef * bf_hi(au);
    }
    out[(size_t)node * 64 + lane] = packbf(vx, vy);
}

// final prop + bias + LayerNorm + ReLU -> f32 out.  V stride 64, U0 stride 192.
__global__ void prop_ln_kernel(const unsigned int* __restrict__ V,
                               const int* __restrict__ rowptr,
                               const int2* __restrict__ csr,
                               const unsigned int* __restrict__ U0,
                               const float* __restrict__ b,
                               const float* __restrict__ g,
                               const float* __restrict__ bt,
                               float* __restrict__ out, int n) {
    int wib = threadIdx.x >> 6;
    int lane = threadIdx.x & 63;
    int node = blockIdx.x * (blockDim.x >> 6) + wib;
    if (node >= n) return;

    float ax = 0.0f, ay = 0.0f;
    int beg = rowptr[node], end = rowptr[node + 1];
    int i = beg;
    for (; i + 16 <= end; i += 16) {
        int2 e[16];
#pragma unroll
        for (int k = 0; k < 16; ++k) e[k] = csr[i + k];
        unsigned int u[16];
#pragma unroll
        for (int k = 0; k < 16; ++k) u[k] = V[(size_t)e[k].x * 64 + lane];
#pragma unroll
        for (int k = 0; k < 16; ++k) {
            float wk = __int_as_float(e[k].y);
            ax += wk * bf_lo(u[k]);
            ay += wk * bf_hi(u[k]);
        }
    }
    for (; i + 8 <= end; i += 8) {
        int2 e[8];
#pragma unroll
        for (int k = 0; k < 8; ++k) e[k] = csr[i + k];
        unsigned int u[8];
#pragma unroll
        for (int k = 0; k < 8; ++k) u[k] = V[(size_t)e[k].x * 64 + lane];
#pragma unroll
        for (int k = 0; k < 8; ++k) {
            float wk = __int_as_float(e[k].y);
            ax += wk * bf_lo(u[k]);
            ay += wk * bf_hi(u[k]);
        }
    }
    for (; i + 2 <= end; i += 2) {
        int2 e0 = csr[i], e1 = csr[i + 1];
        unsigned int u0 = V[(size_t)e0.x * 64 + lane];
        unsigned int u1 = V[(size_t)e1.x * 64 + lane];
        float w0 = __int_as_float(e0.y), w1 = __int_as_float(e1.y);
        ax += w0 * bf_lo(u0) + w1 * bf_lo(u1);
        ay += w0 * bf_hi(u0) + w1 * bf_hi(u1);
    }
    if (i < end) {
        int2 e0 = csr[i];
        unsigned int u0 = V[(size_t)e0.x * 64 + lane];
        float w0 = __int_as_float(e0.y);
        ax += w0 * bf_lo(u0);
        ay += w0 * bf_hi(u0);
    }

    unsigned int au = U0[(size_t)node * 192 + lane];
    float px = ax + bf_lo(au) + b[2 * lane];
    float py = ay + bf_hi(au) + b[2 * lane + 1];

    float s = px + py;
#pragma unroll
    for (int o = 1; o < 64; o <<= 1) s += __shfl_xor(s, o);
    float mu = s * (1.0f / 128.0f);
    float dx = px - mu, dy = py - mu;
    float q = dx * dx + dy * dy;
#pragma unroll
    for (int o = 1; o < 64; o <<= 1) q += __shfl_xor(q, o);
    float rs = rsqrtf(q * (1.0f / 128.0f) + 1e-5f);

    float yx = dx * rs * g[2 * lane] + bt[2 * lane];
    float yy = dy * rs * g[2 * lane + 1] + bt[2 * lane + 1];
    yx = yx > 0.0f ? yx : 0.0f;
    yy = yy > 0.0f ? yy : 0.0f;
    float2 o2 = make_float2(yx, yy);
    *reinterpret_cast<float2*>(out + (size_t)node * 128 + 2 * lane) = o2;
}

// ---------------- gemm1: [x|T1|T2] @ Bt1^T + b1 -> LN -> ReLU -> bf16 h1 ----------------
// EXACT round-14 kernel (validated green twice). 256 thr / 4 waves, BM=64
// BN=256 BK=64, single-buffer 2-barrier loop. FROZEN: five restructure
// attempts (512-thr r9-r11, 2-deep prefetch r13, BM=32 r15) all failed
// validation — do not modify tile, wave layout, or sync structure.

__global__ __launch_bounds__(256) void gemm1_ln_kernel(
        const unsigned short* __restrict__ A0, const unsigned short* __restrict__ A1,
        const unsigned short* __restrict__ A2, const unsigned short* __restrict__ Bt,
        const float* __restrict__ bias, const float* __restrict__ g,
        const float* __restrict__ bt, unsigned short* __restrict__ Hout, int N) {
    __shared__ __align__(16) unsigned short As[64][72];
    __shared__ __align__(16) unsigned short Bs[256][72];
    __shared__ float redS[4][64];
    __shared__ float redQ[4][64];

    int row0 = blockIdx.x * 64;
    int tid = threadIdx.x;
    int lane = tid & 63;
    int wave = tid >> 6;
    int wc = wave * 64;

    f32x4 acc[4][4];
#pragma unroll
    for (int i = 0; i < 4; ++i)
#pragma unroll
        for (int j = 0; j < 4; ++j) acc[i][j] = (f32x4)0.0f;

    int arow = tid >> 2;            // 0..63
    int ach = (tid & 3) * 16;       // 0,16,32,48 (shorts)
    int brow = tid >> 3;            // 0..31
    int bch = (tid & 7) * 8;        // 0..56 (shorts)
    int gra = min(row0 + arow, N - 1);   // clamp: OOB rows computed, never stored

    for (int ks = 0; ks < 6; ++ks) {
        int kg = ks * 64;                 // global K offset (0..320)
        int seg = kg >> 7;                // 0,0,1,1,2,2
        int kk = kg & 127;                // 0,64 within segment
        const unsigned short* Aseg = (seg == 0) ? A0 : (seg == 1 ? A1 : A2);
        // A tile: 64 rows x 64 shorts, 2 uint4 per thread
        *reinterpret_cast<uint4*>(&As[arow][ach]) =
            *reinterpret_cast<const uint4*>(Aseg + (size_t)gra * 128 + kk + ach);
        *reinterpret_cast<uint4*>(&As[arow][ach + 8]) =
            *reinterpret_cast<const uint4*>(Aseg + (size_t)gra * 128 + kk + ach + 8);
        // B tile: 256 rows x 64 shorts, 8 uint4 per thread (rows p*32+brow)
#pragma unroll
        for (int p = 0; p < 8; ++p) {
            int r = p * 32 + brow;
            *reinterpret_cast<uint4*>(&Bs[r][bch]) =
                *reinterpret_cast<const uint4*>(Bt + (size_t)r * 384 + kg + bch);
        }
        __syncthreads();

        int fr = lane & 15;
        int kh = (lane >> 4) * 8;
        bf16x8 af[4], af2[4], bfr[4], bfr2[4];
#pragma unroll
        for (int i = 0; i < 4; ++i) {
            af[i]  = *reinterpret_cast<const bf16x8*>(&As[i * 16 + fr][kh]);
            af2[i] = *reinterpret_cast<const bf16x8*>(&As[i * 16 + fr][32 + kh]);
        }
#pragma unroll
        for (int j = 0; j < 4; ++j) {
            bfr[j]  = *reinterpret_cast<const bf16x8*>(&Bs[wc + j * 16 + fr][kh]);
            bfr2[j] = *reinterpret_cast<const bf16x8*>(&Bs[wc + j * 16 + fr][32 + kh]);
        }
#pragma unroll
        for (int i = 0; i < 4; ++i)
#pragma unroll
            for (int j = 0; j < 4; ++j) {
                acc[i][j] = __builtin_amdgcn_mfma_f32_16x16x32_bf16(af[i],  bfr[j],  acc[i][j], 0, 0, 0);
                acc[i][j] = __builtin_amdgcn_mfma_f32_16x16x32_bf16(af2[i], bfr2[j], acc[i][j], 0, 0, 0);
            }
        __syncthreads();
    }

    int fc = lane & 15;
    int fq = lane >> 4;
    float bcol[4], gcol[4], btcol[4];
#pragma unroll
    for (int j = 0; j < 4; ++j) {
        int c = wc + j * 16 + fc;
        bcol[j] = bias[c];
        gcol[j] = g[c];
        btcol[j] = bt[c];
    }
#pragma unroll
    for (int i = 0; i < 4; ++i)
#pragma unroll
        for (int j = 0; j < 4; ++j)
#pragma unroll
            for (int v = 0; v < 4; ++v) acc[i][j][v] += bcol[j];

#pragma unroll
    for (int i = 0; i < 4; ++i) {
#pragma unroll
        for (int v = 0; v < 4; ++v) {
            float s = 0.0f, q = 0.0f;
#pragma unroll
            for (int j = 0; j < 4; ++j) {
                float val = acc[i][j][v];
                s += val;
                q += val * val;
            }
#pragma unroll
            for (int o = 1; o < 16; o <<= 1) {
                s += __shfl_xor(s, o);
                q += __shfl_xor(q, o);
            }
            if (fc == 0) {
                int r = i * 16 + fq * 4 + v;
                redS[wave][r] = s;
                redQ[wave][r] = q;
            }
        }
    }
    __syncthreads();

#pragma unroll
    for (int i = 0; i < 4; ++i) {
#pragma unroll
        for (int v = 0; v < 4; ++v) {
            int r = i * 16 + fq * 4 + v;
            float S = redS[0][r] + redS[1][r] + redS[2][r] + redS[3][r];
            float Q = redQ[0][r] + redQ[1][r] + redQ[2][r] + redQ[3][r];
            float mu = S * (1.0f / 256.0f);
            float var = Q * (1.0f / 256.0f) - mu * mu;
            float rsg = rsqrtf(var + 1e-5f);
            int gr = row0 + r;
            if (gr < N) {
#pragma unroll
                for (int j = 0; j < 4; ++j) {
                    float y = (acc[i][j][v] - mu) * rsg * gcol[j] + btcol[j];
                    y = y > 0.0f ? y : 0.0f;
                    Hout[(size_t)gr * 256 + wc + j * 16 + fc] = f2bf(y);
                }
            }
        }
    }
}

// ---------------- gemm2: h1 @ Btc^T -> U [N][384] bf16 ----------------
// EXACT round-14 kernel (validated green twice). FROZEN like gemm1.

__global__ __launch_bounds__(256) void gemm2_kernel(
        const unsigned short* __restrict__ A, const unsigned short* __restrict__ Btc,
        unsigned short* __restrict__ U, int N, int ncol) {
    __shared__ __align__(16) unsigned short As[64][72];
    __shared__ __align__(16) unsigned short Bs[128][72];

    int nwg = gridDim.x;
    int q = nwg >> 3, r = nwg & 7;
    int xcd = blockIdx.x & 7, idx = blockIdx.x >> 3;
    int wgid = (xcd < r ? xcd * (q + 1) : r * (q + 1) + (xcd - r) * q) + idx;

    int row0 = (wgid / ncol) * 64;
    int col0 = (wgid % ncol) * 128;

    int tid = threadIdx.x;
    int lane = tid & 63;
    int wave = tid >> 6;
    int wc = wave * 32;

    f32x4 acc[4][2];
#pragma unroll
    for (int i = 0; i < 4; ++i)
#pragma unroll
        for (int j = 0; j < 2; ++j) acc[i][j] = (f32x4)0.0f;

    int arow = tid >> 2;            // 0..63
    int ach = (tid & 3) * 16;       // 0,16,32,48
    int brow = tid >> 3;            // 0..31
    int bch = (tid & 7) * 8;        // 0..56
    int gra = min(row0 + arow, N - 1);

    for (int ks = 0; ks < 4; ++ks) {
        int kg = ks * 64;
        *reinterpret_cast<uint4*>(&As[arow][ach]) =
            *reinterpret_cast<const uint4*>(A + (size_t)gra * 256 + kg + ach);
        *reinterpret_cast<uint4*>(&As[arow][ach + 8]) =
            *reinterpret_cast<const uint4*>(A + (size_t)gra * 256 + kg + ach + 8);
#pragma unroll
        for (int p = 0; p < 4; ++p) {
            int rr = p * 32 + brow;
            *reinterpret_cast<uint4*>(&Bs[rr][bch]) =
                *reinterpret_cast<const uint4*>(Btc + (size_t)(col0 + rr) * 256 + kg + bch);
        }
        __syncthreads();

        int fr = lane & 15;
        int kh = (lane >> 4) * 8;
        bf16x8 af[4], af2[4], bfr[2], bfr2[2];
#pragma unroll
        for (int i = 0; i < 4; ++i) {
            af[i]  = *reinterpret_cast<const bf16x8*>(&As[i * 16 + fr][kh]);
            af2[i] = *reinterpret_cast<const bf16x8*>(&As[i * 16 + fr][32 + kh]);
        }
#pragma unroll
        for (int j = 0; j < 2; ++j) {
            bfr[j]  = *reinterpret_cast<const bf16x8*>(&Bs[wc + j * 16 + fr][kh]);
            bfr2[j] = *reinterpret_cast<const bf16x8*>(&Bs[wc + j * 16 + fr][32 + kh]);
        }
#pragma unroll
        for (int i = 0; i < 4; ++i)
#pragma unroll
            for (int j = 0; j < 2; ++j) {
                acc[i][j] = __builtin_amdgcn_mfma_f32_16x16x32_bf16(af[i],  bfr[j],  acc[i][j], 0, 0, 0);
                acc[i][j] = __builtin_amdgcn_mfma_f32_16x16x32_bf16(af2[i], bfr2[j], acc[i][j], 0, 0, 0);
            }
        __syncthreads();
    }

    int fc = lane & 15;
    int frr = (lane >> 4) * 4;
#pragma unroll
    for (int i = 0; i < 4; ++i) {
#pragma unroll
        for (int v = 0; v < 4; ++v) {
            int gr = row0 + i * 16 + frr + v;
            if (gr < N) {
#pragma unroll
                for (int j = 0; j < 2; ++j) {
                    int gc = col0 + wc + j * 16 + fc;
                    U[(size_t)gr * 384 + gc] = f2bf(acc[i][j][v]);
                }
            }
        }
    }
}

// ---------------- host launch ----------------

extern "C" void kernel_launch(void* const* d_in, const int* in_sizes, int n_in,
                              void* d_out, int out_size, void* d_ws, size_t ws_size,
                              hipStream_t stream) {
    const int N = N_NODES;
    const float* x  = (const float*)d_in[0];
    const int*  ei  = (const int*)d_in[1];
    const float* W1 = (const float*)d_in[2];
    const float* b1 = (const float*)d_in[3];
    const float* g1 = (const float*)d_in[4];
    const float* bt1 = (const float*)d_in[5];
    const float* W2 = (const float*)d_in[6];
    const float* b2 = (const float*)d_in[7];
    const float* g2 = (const float*)d_in[8];
    const float* bt2 = (const float*)d_in[9];
    float* out = (float*)d_out;

    const int E = in_sizes[1] / 2;
    const int* src = ei;
    const int* dst = ei + E;
    const int chunk = (E + NCHUNK - 1) / NCHUNK;

    // workspace carve (256B aligned)
    char* w = (char*)d_ws;
    auto alloc = [&](size_t bytes) { char* p = w; w += (bytes + 255) & ~(size_t)255; return p; };
    int* pd      = (int*)alloc((size_t)NCHUNK * TOTR * 4);
    int* pc      = (int*)alloc((size_t)NCHUNK * TOTR * 4);
    int* cnt     = (int*)alloc((size_t)N * 4);
    int* excl    = (int*)alloc((size_t)N * 4);
    int* bsum    = (int*)alloc(64 * 4);
    int* rowptr  = (int*)alloc((size_t)(N + 1) * 4);
    int2* csr    = (int2*)alloc((size_t)E * 8);
    float* dinv  = (float*)alloc((size_t)N * 4);
    unsigned short* xb  = (unsigned short*)alloc((size_t)N * 128 * 2);
    unsigned short* T1  = (unsigned short*)alloc((size_t)N * 128 * 2);
    unsigned short* T2  = (unsigned short*)alloc((size_t)N * 128 * 2);
    unsigned short* h1b = (unsigned short*)alloc((size_t)N * 256 * 2);
    unsigned short* U   = (unsigned short*)alloc((size_t)N * 384 * 2);
    unsigned short* V   = (unsigned short*)alloc((size_t)N * 128 * 2);
    unsigned short* Bt1 = (unsigned short*)alloc((size_t)256 * 384 * 2);
    unsigned short* Btc = (unsigned short*)alloc((size_t)384 * 256 * 2);
    (void)ws_size;

    const int TPB = 256;
    const int NB = (N + 1023) / 1024;

    // --- preprocessing: privatized histograms + atomic-free CSR placement ---
    hipLaunchKernelGGL(hist_priv_kernel, dim3(NCHUNK * NRANGE), dim3(1024), 0, stream,
                       src, dst, E, chunk, pd, pc);
    hipLaunchKernelGGL(reduce_chunks_kernel, dim3((TOTR + TPB - 1) / TPB), dim3(TPB), 0, stream,
                       pd, pc, dinv, cnt, N);
    hipLaunchKernelGGL(scan1_kernel, dim3(NB), dim3(1024), 0, stream, cnt, excl, bsum, N);
    hipLaunchKernelGGL(scan2_kernel, dim3(1), dim3(64), 0, stream, bsum, NB);
    hipLaunchKernelGGL(scan3_kernel, dim3(NB), dim3(1024), 0, stream, excl, bsum, cnt, rowptr, N);
    hipLaunchKernelGGL(csr_place_kernel, dim3(NCHUNK * NRANGE), dim3(1024), 0, stream,
                       src, dst, E, chunk, pc, rowptr, dinv, csr, N);
    hipLaunchKernelGGL(cvt_bf_kernel, dim3((N * 128 / 4 + TPB - 1) / TPB), dim3(TPB), 0, stream,
                       x, xb, (size_t)N * 128 / 4);
    hipLaunchKernelGGL(wtrans1_kernel, dim3((3 * 128 * 256 + TPB - 1) / TPB), dim3(TPB), 0, stream, W1, Bt1);
    hipLaunchKernelGGL(wtrans2_kernel, dim3((384 * 256 + TPB - 1) / TPB), dim3(TPB), 0, stream, W2, Btc);

    const int gridW = (N + 3) / 4;   // 4 waves per block, 1 node per wave

    // --- layer 1: props (D=128) then GEMM+LN ---
    hipLaunchKernelGGL(prop_kernel, dim3(gridW), dim3(TPB), 0, stream,
                       (const unsigned int*)xb, 64, rowptr, csr,
                       (const unsigned int*)nullptr, 0, 1.0f, 0.0f,
                       (unsigned int*)T1, N);
    hipLaunchKernelGGL(prop_kernel, dim3(gridW), dim3(TPB), 0, stream,
                       (const unsigned int*)T1, 64, rowptr, csr,
                       (const unsigned int*)xb, 64, 2.0f, -1.0f,
                       (unsigned int*)T2, N);
    hipLaunchKernelGGL(gemm1_ln_kernel, dim3((N + 63) / 64), dim3(256), 0, stream,
                       xb, T1, T2, Bt1, b1, g1, bt1, h1b, N);

    // --- layer 2: GEMM first, then props in 128-dim ---
    {
        int nrow = (N + 63) / 64, ncol = 3;
        hipLaunchKernelGGL(gemm2_kernel, dim3(nrow * ncol), dim3(256), 0, stream,
                           h1b, Btc, U, N, ncol);
    }
    // v = L(u2) + u1
    hipLaunchKernelGGL(prop_kernel, dim3(gridW), dim3(TPB), 0, stream,
                       (const unsigned int*)U + 128, 192, rowptr, csr,
                       (const unsigned int*)U + 64, 192, 1.0f, 1.0f,
                       (unsigned int*)V, N);
    // out = LN(L(v) + u0 + b2) -> relu
    hipLaunchKernelGGL(prop_ln_kernel, dim3(gridW), dim3(TPB), 0, stream,
                       (const unsigned int*)V, rowptr, csr,
                       (const unsigned int*)U, b2, g2, bt2, out, N);
}

// Round 18
// 254.333 us; speedup vs baseline: 1.0257x; 1.0257x over previous
//
#include <hip/hip_runtime.h>

#define N_NODES 50000
#define NRANGE 8
#define RNG 6400          // NRANGE*RNG = 51200 >= N
#define TOTR (NRANGE * RNG)
#define NCHUNK 32

using f32x4  = __attribute__((ext_vector_type(4))) float;
using bf16x8 = __attribute__((ext_vector_type(8))) __bf16;

__device__ __forceinline__ unsigned short f2bf(float f) {
    unsigned int b = __float_as_uint(f);
    unsigned int r = (b + 0x7FFFu + ((b >> 16) & 1u)) >> 16;   // RNE
    return (unsigned short)r;
}
__device__ __forceinline__ float bf_lo(unsigned int u) { return __uint_as_float(u << 16); }
__device__ __forceinline__ float bf_hi(unsigned int u) { return __uint_as_float(u & 0xFFFF0000u); }
__device__ __forceinline__ unsigned int packbf(float x, float y) {
    return ((unsigned int)f2bf(y) << 16) | f2bf(x);
}

// ---------------- utility ----------------

__global__ void cvt_bf_kernel(const float* __restrict__ in, unsigned short* __restrict__ out, size_t n4) {
    size_t i = (size_t)blockIdx.x * blockDim.x + threadIdx.x;
    if (i < n4) {
        float4 v = *reinterpret_cast<const float4*>(in + i * 4);
        ushort4 o;
        o.x = f2bf(v.x); o.y = f2bf(v.y); o.z = f2bf(v.z); o.w = f2bf(v.w);
        *reinterpret_cast<ushort4*>(out + i * 4) = o;
    }
}

// W1: [3][128][256] f32 -> Bt1: [256][384] bf16
__global__ void wtrans1_kernel(const float* __restrict__ W, unsigned short* __restrict__ Bt) {
    int i = blockIdx.x * blockDim.x + threadIdx.x;
    if (i < 3 * 128 * 256) {
        int c = i % 256;
        int kg = i / 256;
        Bt[(size_t)c * 384 + kg] = f2bf(W[(size_t)kg * 256 + c]);
    }
}

// W2: [3][256][128] f32 -> Btc: [384][256] bf16 with cols [W0-W2 | W1 | 2*W2]
__global__ void wtrans2_kernel(const float* __restrict__ W, unsigned short* __restrict__ Btc) {
    int i = blockIdx.x * blockDim.x + threadIdx.x;
    if (i < 384 * 256) {
        int k = i % 256;
        int cc = i / 256;
        int seg = cc >> 7, c = cc & 127;
        float v;
        if (seg == 0)      v = W[(size_t)k * 128 + c] - W[(size_t)(2 * 256 + k) * 128 + c];
        else if (seg == 1) v = W[(size_t)(256 + k) * 128 + c];
        else               v = 2.0f * W[(size_t)(2 * 256 + k) * 128 + c];
        Btc[(size_t)cc * 256 + k] = f2bf(v);
    }
}

// ---------------- edge preprocessing: privatized LDS histograms ----------------

__global__ __launch_bounds__(1024) void hist_priv_kernel(
        const int* __restrict__ src, const int* __restrict__ dst, int E, int chunk,
        int* __restrict__ pd, int* __restrict__ pc) {     // [NCHUNK][TOTR] each
    __shared__ int lhS[RNG];
    __shared__ int lhD[RNG];
    int r = blockIdx.x & (NRANGE - 1);
    int c = blockIdx.x >> 3;               // NRANGE == 8
    int lo = r * RNG;
    for (int i = threadIdx.x; i < RNG; i += 1024) { lhS[i] = 0; lhD[i] = 0; }
    __syncthreads();
    int e0 = c * chunk, e1 = min(e0 + chunk, E);
    for (int e = e0 + threadIdx.x; e < e1; e += 1024) {
        int s = src[e], d = dst[e];
        if (s != d) {
            unsigned int sr = (unsigned int)(s - lo);
            unsigned int dr = (unsigned int)(d - lo);
            if (sr < RNG) atomicAdd(&lhS[sr], 1);
            if (dr < RNG) atomicAdd(&lhD[dr], 1);
        }
    }
    __syncthreads();
    int base = c * TOTR + lo;
    for (int i = threadIdx.x; i < RNG; i += 1024) {
        pd[base + i] = lhS[i];
        pc[base + i] = lhD[i];
    }
}

__global__ void reduce_chunks_kernel(int* __restrict__ pd, int* __restrict__ pc,
                                     float* __restrict__ dinv, int* __restrict__ cnt, int n) {
    int i = blockIdx.x * blockDim.x + threadIdx.x;
    if (i >= TOTR) return;
    int degs = 0;
#pragma unroll 8
    for (int c = 0; c < NCHUNK; ++c) degs += pd[c * TOTR + i];
    int run = 0;
#pragma unroll 8
    for (int c = 0; c < NCHUNK; ++c) {
        int v = pc[c * TOTR + i];
        pc[c * TOTR + i] = run;
        run += v;
    }
    if (i < n) {
        dinv[i] = degs > 0 ? rsqrtf((float)degs) : 0.0f;
        cnt[i] = run;
    }
}

// --- 3-phase scan over cnt -> rowptr ---

__global__ __launch_bounds__(1024) void scan1_kernel(const int* __restrict__ cnt,
                                                     int* __restrict__ excl,
                                                     int* __restrict__ bsum, int n) {
    __shared__ int wsum[16];
    int tid = threadIdx.x, lane = tid & 63, wid = tid >> 6;
    int i = blockIdx.x * 1024 + tid;
    int v = (i < n) ? cnt[i] : 0;
    int x = v;
#pragma unroll
    for (int o = 1; o < 64; o <<= 1) { int y = __shfl_up(x, o); if (lane >= o) x += y; }
    if (lane == 63) wsum[wid] = x;
    __syncthreads();
    if (tid < 16) {
        int s = wsum[tid];
#pragma unroll
        for (int o = 1; o < 16; o <<= 1) { int y = __shfl_up(s, o); if (tid >= o) s += y; }
        wsum[tid] = s;
    }
    __syncthreads();
    int base = (wid > 0 ? wsum[wid - 1] : 0);
    if (i < n) excl[i] = base + x - v;
    if (tid == 0) bsum[blockIdx.x] = wsum[15];
}

__global__ void scan2_kernel(int* __restrict__ bsum, int nb) {
    int t = threadIdx.x;                   // single wave, nb <= 64
    int v = (t < nb) ? bsum[t] : 0;
    int x = v;
#pragma unroll
    for (int o = 1; o < 64; o <<= 1) { int y = __shfl_up(x, o); if (t >= o) x += y; }
    if (t < nb) bsum[t] = x - v;           // exclusive
}

__global__ __launch_bounds__(1024) void scan3_kernel(const int* __restrict__ excl,
                                                     const int* __restrict__ bsum,
                                                     const int* __restrict__ cnt,
                                                     int* __restrict__ rowptr, int n) {
    int i = blockIdx.x * 1024 + threadIdx.x;
    if (i < n) {
        int rp = excl[i] + bsum[blockIdx.x];
        rowptr[i] = rp;
        if (i == n - 1) rowptr[n] = rp + cnt[i];
    }
}

// CSR placement with LDS cursors. csr packed as int2 {src, bitcast(fp32 w)}.
// NOTE (r16 lesson): placement order is nondeterministic (atomic cursors), so
// gather summation order varies across replays. Weights must stay FP32 —
// bf16-packing them (r16) pushed replay-to-replay drift past threshold.
__global__ __launch_bounds__(1024) void csr_place_kernel(
        const int* __restrict__ src, const int* __restrict__ dst, int E, int chunk,
        const int* __restrict__ pc, const int* __restrict__ rowptr,
        const float* __restrict__ dinv,
        int2* __restrict__ csr, int n) {
    __shared__ int cur[RNG];
    __shared__ float dloc[RNG];
    int r = blockIdx.x & (NRANGE - 1);
    int c = blockIdx.x >> 3;
    int lo = r * RNG;
    for (int i = threadIdx.x; i < RNG; i += 1024) {
        int node = lo + i;
        if (node < n) {
            cur[i] = rowptr[node] + pc[c * TOTR + node];
            dloc[i] = dinv[node];
        }
    }
    __syncthreads();
    int e0 = c * chunk, e1 = min(e0 + chunk, E);
    for (int e = e0 + threadIdx.x; e < e1; e += 1024) {
        int s = src[e], d = dst[e];
        unsigned int dr = (unsigned int)(d - lo);
        if (s != d && dr < RNG) {
            int pos = atomicAdd(&cur[dr], 1);
            csr[pos] = make_int2(s, __float_as_int(-dinv[s] * dloc[dr]));
        }
    }
}

// ---------------- CSR gather propagation, D=128 bf16, f32 accum ----------------
// 8-wide edge unroll: VALIDATED OPTIMUM (r12/r14 green). 4-wide is slower
// (fewer outstanding loads); 16-wide (r17) is occupancy-limited (+32 VGPR) and
// net-negative. Do not change the unroll width.

__global__ void prop_kernel(const unsigned int* __restrict__ H, int hs,
                            const int* __restrict__ rowptr,
                            const int2* __restrict__ csr,
                            const unsigned int* __restrict__ add, int as_,
                            float scale, float coef,
                            unsigned int* __restrict__ out, int n) {
    int wib = threadIdx.x >> 6;
    int lane = threadIdx.x & 63;
    int node = blockIdx.x * (blockDim.x >> 6) + wib;
    if (node >= n) return;

    float ax = 0.0f, ay = 0.0f;
    int beg = rowptr[node], end = rowptr[node + 1];
    int i = beg;
    for (; i + 8 <= end; i += 8) {
        int2 e[8];
#pragma unroll
        for (int k = 0; k < 8; ++k) e[k] = csr[i + k];
        unsigned int u[8];
#pragma unroll
        for (int k = 0; k < 8; ++k) u[k] = H[(size_t)e[k].x * hs + lane];
#pragma unroll
        for (int k = 0; k < 8; ++k) {
            float wk = __int_as_float(e[k].y);
            ax += wk * bf_lo(u[k]);
            ay += wk * bf_hi(u[k]);
        }
    }
    for (; i + 2 <= end; i += 2) {
        int2 e0 = csr[i], e1 = csr[i + 1];
        unsigned int u0 = H[(size_t)e0.x * hs + lane];
        unsigned int u1 = H[(size_t)e1.x * hs + lane];
        float w0 = __int_as_float(e0.y), w1 = __int_as_float(e1.y);
        ax += w0 * bf_lo(u0) + w1 * bf_lo(u1);
        ay += w0 * bf_hi(u0) + w1 * bf_hi(u1);
    }
    if (i < end) {
        int2 e0 = csr[i];
        unsigned int u0 = H[(size_t)e0.x * hs + lane];
        float w0 = __int_as_float(e0.y);
        ax += w0 * bf_lo(u0);
        ay += w0 * bf_hi(u0);
    }

    float vx = scale * ax, vy = scale * ay;
    if (add) {
        unsigned int au = add[(size_t)node * as_ + lane];
        vx += coef * bf_lo(au);
        vy += coef * bf_hi(au);
    }
    out[(size_t)node * 64 + lane] = packbf(vx, vy);
}

// final prop + bias + LayerNorm + ReLU -> f32 out.  V stride 64, U0 stride 192.
__global__ void prop_ln_kernel(const unsigned int* __restrict__ V,
                               const int* __restrict__ rowptr,
                               const int2* __restrict__ csr,
                               const unsigned int* __restrict__ U0,
                               const float* __restrict__ b,
                               const float* __restrict__ g,
                               const float* __restrict__ bt,
                               float* __restrict__ out, int n) {
    int wib = threadIdx.x >> 6;
    int lane = threadIdx.x & 63;
    int node = blockIdx.x * (blockDim.x >> 6) + wib;
    if (node >= n) return;

    float ax = 0.0f, ay = 0.0f;
    int beg = rowptr[node], end = rowptr[node + 1];
    int i = beg;
    for (; i + 8 <= end; i += 8) {
        int2 e[8];
#pragma unroll
        for (int k = 0; k < 8; ++k) e[k] = csr[i + k];
        unsigned int u[8];
#pragma unroll
        for (int k = 0; k < 8; ++k) u[k] = V[(size_t)e[k].x * 64 + lane];
#pragma unroll
        for (int k = 0; k < 8; ++k) {
            float wk = __int_as_float(e[k].y);
            ax += wk * bf_lo(u[k]);
            ay += wk * bf_hi(u[k]);
        }
    }
    for (; i + 2 <= end; i += 2) {
        int2 e0 = csr[i], e1 = csr[i + 1];
        unsigned int u0 = V[(size_t)e0.x * 64 + lane];
        unsigned int u1 = V[(size_t)e1.x * 64 + lane];
        float w0 = __int_as_float(e0.y), w1 = __int_as_float(e1.y);
        ax += w0 * bf_lo(u0) + w1 * bf_lo(u1);
        ay += w0 * bf_hi(u0) + w1 * bf_hi(u1);
    }
    if (i < end) {
        int2 e0 = csr[i];
        unsigned int u0 = V[(size_t)e0.x * 64 + lane];
        float w0 = __int_as_float(e0.y);
        ax += w0 * bf_lo(u0);
        ay += w0 * bf_hi(u0);
    }

    unsigned int au = U0[(size_t)node * 192 + lane];
    float px = ax + bf_lo(au) + b[2 * lane];
    float py = ay + bf_hi(au) + b[2 * lane + 1];

    float s = px + py;
#pragma unroll
    for (int o = 1; o < 64; o <<= 1) s += __shfl_xor(s, o);
    float mu = s * (1.0f / 128.0f);
    float dx = px - mu, dy = py - mu;
    float q = dx * dx + dy * dy;
#pragma unroll
    for (int o = 1; o < 64; o <<= 1) q += __shfl_xor(q, o);
    float rs = rsqrtf(q * (1.0f / 128.0f) + 1e-5f);

    float yx = dx * rs * g[2 * lane] + bt[2 * lane];
    float yy = dy * rs * g[2 * lane + 1] + bt[2 * lane + 1];
    yx = yx > 0.0f ? yx : 0.0f;
    yy = yy > 0.0f ? yy : 0.0f;
    float2 o2 = make_float2(yx, yy);
    *reinterpret_cast<float2*>(out + (size_t)node * 128 + 2 * lane) = o2;
}

// ---------------- gemm1: [x|T1|T2] @ Bt1^T + b1 -> LN -> ReLU -> bf16 h1 ----------------
// EXACT round-14 kernel (validated green twice at 254.7us). 256 thr / 4 waves,
// BM=64 BN=256 BK=64, single-buffer 2-barrier loop. FROZEN: six restructure
// attempts (512-thr r9-r11, 2-deep prefetch r13, BM=32 r15) all failed
// validation — do not modify tile, wave layout, or sync structure.

__global__ __launch_bounds__(256) void gemm1_ln_kernel(
        const unsigned short* __restrict__ A0, const unsigned short* __restrict__ A1,
        const unsigned short* __restrict__ A2, const unsigned short* __restrict__ Bt,
        const float* __restrict__ bias, const float* __restrict__ g,
        const float* __restrict__ bt, unsigned short* __restrict__ Hout, int N) {
    __shared__ __align__(16) unsigned short As[64][72];
    __shared__ __align__(16) unsigned short Bs[256][72];
    __shared__ float redS[4][64];
    __shared__ float redQ[4][64];

    int row0 = blockIdx.x * 64;
    int tid = threadIdx.x;
    int lane = tid & 63;
    int wave = tid >> 6;
    int wc = wave * 64;

    f32x4 acc[4][4];
#pragma unroll
    for (int i = 0; i < 4; ++i)
#pragma unroll
        for (int j = 0; j < 4; ++j) acc[i][j] = (f32x4)0.0f;

    int arow = tid >> 2;            // 0..63
    int ach = (tid & 3) * 16;       // 0,16,32,48 (shorts)
    int brow = tid >> 3;            // 0..31
    int bch = (tid & 7) * 8;        // 0..56 (shorts)
    int gra = min(row0 + arow, N - 1);   // clamp: OOB rows computed, never stored

    for (int ks = 0; ks < 6; ++ks) {
        int kg = ks * 64;                 // global K offset (0..320)
        int seg = kg >> 7;                // 0,0,1,1,2,2
        int kk = kg & 127;                // 0,64 within segment
        const unsigned short* Aseg = (seg == 0) ? A0 : (seg == 1 ? A1 : A2);
        // A tile: 64 rows x 64 shorts, 2 uint4 per thread
        *reinterpret_cast<uint4*>(&As[arow][ach]) =
            *reinterpret_cast<const uint4*>(Aseg + (size_t)gra * 128 + kk + ach);
        *reinterpret_cast<uint4*>(&As[arow][ach + 8]) =
            *reinterpret_cast<const uint4*>(Aseg + (size_t)gra * 128 + kk + ach + 8);
        // B tile: 256 rows x 64 shorts, 8 uint4 per thread (rows p*32+brow)
#pragma unroll
        for (int p = 0; p < 8; ++p) {
            int r = p * 32 + brow;
            *reinterpret_cast<uint4*>(&Bs[r][bch]) =
                *reinterpret_cast<const uint4*>(Bt + (size_t)r * 384 + kg + bch);
        }
        __syncthreads();

        int fr = lane & 15;
        int kh = (lane >> 4) * 8;
        bf16x8 af[4], af2[4], bfr[4], bfr2[4];
#pragma unroll
        for (int i = 0; i < 4; ++i) {
            af[i]  = *reinterpret_cast<const bf16x8*>(&As[i * 16 + fr][kh]);
            af2[i] = *reinterpret_cast<const bf16x8*>(&As[i * 16 + fr][32 + kh]);
        }
#pragma unroll
        for (int j = 0; j < 4; ++j) {
            bfr[j]  = *reinterpret_cast<const bf16x8*>(&Bs[wc + j * 16 + fr][kh]);
            bfr2[j] = *reinterpret_cast<const bf16x8*>(&Bs[wc + j * 16 + fr][32 + kh]);
        }
#pragma unroll
        for (int i = 0; i < 4; ++i)
#pragma unroll
            for (int j = 0; j < 4; ++j) {
                acc[i][j] = __builtin_amdgcn_mfma_f32_16x16x32_bf16(af[i],  bfr[j],  acc[i][j], 0, 0, 0);
                acc[i][j] = __builtin_amdgcn_mfma_f32_16x16x32_bf16(af2[i], bfr2[j], acc[i][j], 0, 0, 0);
            }
        __syncthreads();
    }

    int fc = lane & 15;
    int fq = lane >> 4;
    float bcol[4], gcol[4], btcol[4];
#pragma unroll
    for (int j = 0; j < 4; ++j) {
        int c = wc + j * 16 + fc;
        bcol[j] = bias[c];
        gcol[j] = g[c];
        btcol[j] = bt[c];
    }
#pragma unroll
    for (int i = 0; i < 4; ++i)
#pragma unroll
        for (int j = 0; j < 4; ++j)
#pragma unroll
            for (int v = 0; v < 4; ++v) acc[i][j][v] += bcol[j];

#pragma unroll
    for (int i = 0; i < 4; ++i) {
#pragma unroll
        for (int v = 0; v < 4; ++v) {
            float s = 0.0f, q = 0.0f;
#pragma unroll
            for (int j = 0; j < 4; ++j) {
                float val = acc[i][j][v];
                s += val;
                q += val * val;
            }
#pragma unroll
            for (int o = 1; o < 16; o <<= 1) {
                s += __shfl_xor(s, o);
                q += __shfl_xor(q, o);
            }
            if (fc == 0) {
                int r = i * 16 + fq * 4 + v;
                redS[wave][r] = s;
                redQ[wave][r] = q;
            }
        }
    }
    __syncthreads();

#pragma unroll
    for (int i = 0; i < 4; ++i) {
#pragma unroll
        for (int v = 0; v < 4; ++v) {
            int r = i * 16 + fq * 4 + v;
            float S = redS[0][r] + redS[1][r] + redS[2][r] + redS[3][r];
            float Q = redQ[0][r] + redQ[1][r] + redQ[2][r] + redQ[3][r];
            float mu = S * (1.0f / 256.0f);
            float var = Q * (1.0f / 256.0f) - mu * mu;
            float rsg = rsqrtf(var + 1e-5f);
            int gr = row0 + r;
            if (gr < N) {
#pragma unroll
                for (int j = 0; j < 4; ++j) {
                    float y = (acc[i][j][v] - mu) * rsg * gcol[j] + btcol[j];
                    y = y > 0.0f ? y : 0.0f;
                    Hout[(size_t)gr * 256 + wc + j * 16 + fc] = f2bf(y);
                }
            }
        }
    }
}

// ---------------- gemm2: h1 @ Btc^T -> U [N][384] bf16 ----------------
// EXACT round-14 kernel (validated green twice). FROZEN like gemm1.

__global__ __launch_bounds__(256) void gemm2_kernel(
        const unsigned short* __restrict__ A, const unsigned short* __restrict__ Btc,
        unsigned short* __restrict__ U, int N, int ncol) {
    __shared__ __align__(16) unsigned short As[64][72];
    __shared__ __align__(16) unsigned short Bs[128][72];

    int nwg = gridDim.x;
    int q = nwg >> 3, r = nwg & 7;
    int xcd = blockIdx.x & 7, idx = blockIdx.x >> 3;
    int wgid = (xcd < r ? xcd * (q + 1) : r * (q + 1) + (xcd - r) * q) + idx;

    int row0 = (wgid / ncol) * 64;
    int col0 = (wgid % ncol) * 128;

    int tid = threadIdx.x;
    int lane = tid & 63;
    int wave = tid >> 6;
    int wc = wave * 32;

    f32x4 acc[4][2];
#pragma unroll
    for (int i = 0; i < 4; ++i)
#pragma unroll
        for (int j = 0; j < 2; ++j) acc[i][j] = (f32x4)0.0f;

    int arow = tid >> 2;            // 0..63
    int ach = (tid & 3) * 16;       // 0,16,32,48
    int brow = tid >> 3;            // 0..31
    int bch = (tid & 7) * 8;        // 0..56
    int gra = min(row0 + arow, N - 1);

    for (int ks = 0; ks < 4; ++ks) {
        int kg = ks * 64;
        *reinterpret_cast<uint4*>(&As[arow][ach]) =
            *reinterpret_cast<const uint4*>(A + (size_t)gra * 256 + kg + ach);
        *reinterpret_cast<uint4*>(&As[arow][ach + 8]) =
            *reinterpret_cast<const uint4*>(A + (size_t)gra * 256 + kg + ach + 8);
#pragma unroll
        for (int p = 0; p < 4; ++p) {
            int rr = p * 32 + brow;
            *reinterpret_cast<uint4*>(&Bs[rr][bch]) =
                *reinterpret_cast<const uint4*>(Btc + (size_t)(col0 + rr) * 256 + kg + bch);
        }
        __syncthreads();

        int fr = lane & 15;
        int kh = (lane >> 4) * 8;
        bf16x8 af[4], af2[4], bfr[2], bfr2[2];
#pragma unroll
        for (int i = 0; i < 4; ++i) {
            af[i]  = *reinterpret_cast<const bf16x8*>(&As[i * 16 + fr][kh]);
            af2[i] = *reinterpret_cast<const bf16x8*>(&As[i * 16 + fr][32 + kh]);
        }
#pragma unroll
        for (int j = 0; j < 2; ++j) {
            bfr[j]  = *reinterpret_cast<const bf16x8*>(&Bs[wc + j * 16 + fr][kh]);
            bfr2[j] = *reinterpret_cast<const bf16x8*>(&Bs[wc + j * 16 + fr][32 + kh]);
        }
#pragma unroll
        for (int i = 0; i < 4; ++i)
#pragma unroll
            for (int j = 0; j < 2; ++j) {
                acc[i][j] = __builtin_amdgcn_mfma_f32_16x16x32_bf16(af[i],  bfr[j],  acc[i][j], 0, 0, 0);
                acc[i][j] = __builtin_amdgcn_mfma_f32_16x16x32_bf16(af2[i], bfr2[j], acc[i][j], 0, 0, 0);
            }
        __syncthreads();
    }

    int fc = lane & 15;
    int frr = (lane >> 4) * 4;
#pragma unroll
    for (int i = 0; i < 4; ++i) {
#pragma unroll
        for (int v = 0; v < 4; ++v) {
            int gr = row0 + i * 16 + frr + v;
            if (gr < N) {
#pragma unroll
                for (int j = 0; j < 2; ++j) {
                    int gc = col0 + wc + j * 16 + fc;
                    U[(size_t)gr * 384 + gc] = f2bf(acc[i][j][v]);
                }
            }
        }
    }
}

// ---------------- host launch ----------------

extern "C" void kernel_launch(void* const* d_in, const int* in_sizes, int n_in,
                              void* d_out, int out_size, void* d_ws, size_t ws_size,
                              hipStream_t stream) {
    const int N = N_NODES;
    const float* x  = (const float*)d_in[0];
    const int*  ei  = (const int*)d_in[1];
    const float* W1 = (const float*)d_in[2];
    const float* b1 = (const float*)d_in[3];
    const float* g1 = (const float*)d_in[4];
    const float* bt1 = (const float*)d_in[5];
    const float* W2 = (const float*)d_in[6];
    const float* b2 = (const float*)d_in[7];
    const float* g2 = (const float*)d_in[8];
    const float* bt2 = (const float*)d_in[9];
    float* out = (float*)d_out;

    const int E = in_sizes[1] / 2;
    const int* src = ei;
    const int* dst = ei + E;
    const int chunk = (E + NCHUNK - 1) / NCHUNK;

    // workspace carve (256B aligned)
    char* w = (char*)d_ws;
    auto alloc = [&](size_t bytes) { char* p = w; w += (bytes + 255) & ~(size_t)255; return p; };
    int* pd      = (int*)alloc((size_t)NCHUNK * TOTR * 4);
    int* pc      = (int*)alloc((size_t)NCHUNK * TOTR * 4);
    int* cnt     = (int*)alloc((size_t)N * 4);
    int* excl    = (int*)alloc((size_t)N * 4);
    int* bsum    = (int*)alloc(64 * 4);
    int* rowptr  = (int*)alloc((size_t)(N + 1) * 4);
    int2* csr    = (int2*)alloc((size_t)E * 8);
    float* dinv  = (float*)alloc((size_t)N * 4);
    unsigned short* xb  = (unsigned short*)alloc((size_t)N * 128 * 2);
    unsigned short* T1  = (unsigned short*)alloc((size_t)N * 128 * 2);
    unsigned short* T2  = (unsigned short*)alloc((size_t)N * 128 * 2);
    unsigned short* h1b = (unsigned short*)alloc((size_t)N * 256 * 2);
    unsigned short* U   = (unsigned short*)alloc((size_t)N * 384 * 2);
    unsigned short* V   = (unsigned short*)alloc((size_t)N * 128 * 2);
    unsigned short* Bt1 = (unsigned short*)alloc((size_t)256 * 384 * 2);
    unsigned short* Btc = (unsigned short*)alloc((size_t)384 * 256 * 2);
    (void)ws_size;

    const int TPB = 256;
    const int NB = (N + 1023) / 1024;

    // --- preprocessing: privatized histograms + atomic-free CSR placement ---
    hipLaunchKernelGGL(hist_priv_kernel, dim3(NCHUNK * NRANGE), dim3(1024), 0, stream,
                       src, dst, E, chunk, pd, pc);
    hipLaunchKernelGGL(reduce_chunks_kernel, dim3((TOTR + TPB - 1) / TPB), dim3(TPB), 0, stream,
                       pd, pc, dinv, cnt, N);
    hipLaunchKernelGGL(scan1_kernel, dim3(NB), dim3(1024), 0, stream, cnt, excl, bsum, N);
    hipLaunchKernelGGL(scan2_kernel, dim3(1), dim3(64), 0, stream, bsum, NB);
    hipLaunchKernelGGL(scan3_kernel, dim3(NB), dim3(1024), 0, stream, excl, bsum, cnt, rowptr, N);
    hipLaunchKernelGGL(csr_place_kernel, dim3(NCHUNK * NRANGE), dim3(1024), 0, stream,
                       src, dst, E, chunk, pc, rowptr, dinv, csr, N);
    hipLaunchKernelGGL(cvt_bf_kernel, dim3((N * 128 / 4 + TPB - 1) / TPB), dim3(TPB), 0, stream,
                       x, xb, (size_t)N * 128 / 4);
    hipLaunchKernelGGL(wtrans1_kernel, dim3((3 * 128 * 256 + TPB - 1) / TPB), dim3(TPB), 0, stream, W1, Bt1);
    hipLaunchKernelGGL(wtrans2_kernel, dim3((384 * 256 + TPB - 1) / TPB), dim3(TPB), 0, stream, W2, Btc);

    const int gridW = (N + 3) / 4;   // 4 waves per block, 1 node per wave

    // --- layer 1: props (D=128) then GEMM+LN ---
    hipLaunchKernelGGL(prop_kernel, dim3(gridW), dim3(TPB), 0, stream,
                       (const unsigned int*)xb, 64, rowptr, csr,
                       (const unsigned int*)nullptr, 0, 1.0f, 0.0f,
                       (unsigned int*)T1, N);
    hipLaunchKernelGGL(prop_kernel, dim3(gridW), dim3(TPB), 0, stream,
                       (const unsigned int*)T1, 64, rowptr, csr,
                       (const unsigned int*)xb, 64, 2.0f, -1.0f,
                       (unsigned int*)T2, N);
    hipLaunchKernelGGL(gemm1_ln_kernel, dim3((N + 63) / 64), dim3(256), 0, stream,
                       xb, T1, T2, Bt1, b1, g1, bt1, h1b, N);

    // --- layer 2: GEMM first, then props in 128-dim ---
    {
        int nrow = (N + 63) / 64, ncol = 3;
        hipLaunchKernelGGL(gemm2_kernel, dim3(nrow * ncol), dim3(256), 0, stream,
                           h1b, Btc, U, N, ncol);
    }
    // v = L(u2) + u1
    hipLaunchKernelGGL(prop_kernel, dim3(gridW), dim3(TPB), 0, stream,
                       (const unsigned int*)U + 128, 192, rowptr, csr,
                       (const unsigned int*)U + 64, 192, 1.0f, 1.0f,
                       (unsigned int*)V, N);
    // out = LN(L(v) + u0 + b2) -> relu
    hipLaunchKernelGGL(prop_ln_kernel, dim3(gridW), dim3(TPB), 0, stream,
                       (const unsigned int*)V, rowptr, csr,
                       (const unsigned int*)U, b2, g2, bt2, out, N);
}